// Round 8
// baseline (139.596 us; speedup 1.0000x reference)
//
#include <hip/hip_runtime.h>
#include <stdint.h>

typedef _Float16 half8  __attribute__((ext_vector_type(8)));
typedef float    f32x4  __attribute__((ext_vector_type(4)));
typedef uint32_t u32x4  __attribute__((ext_vector_type(4)));

#define NPIX 61504   // 16 * 62 * 62
#define LPB  3844    // 62*62
#define FIN  288
#define NOUT 64
#define KSPL 72
#define NXPIX 2097152        // 16*32*64*64
#define BFRAG_BYTES 332800   // weight table bytes, padded

// ---------------- cubic B-spline basis: 8 slots, f16-packed ----------------
__device__ inline half8 bspline8(float xv) {
  float u = fmaf(xv, 2.5f, 5.5f);
  float fi = floorf(u);
  int i = (int)fi;
  float t = u - fi, s = 1.0f - t;
  float t2 = t * t, t3 = t2 * t;
  float s2 = s * s, s3 = s2 * s;
  float w3 = t3 * 0.16666667f;
  float w0 = s3 * 0.16666667f;
  float w1 = fmaf(0.5f, t3, -t2) + 0.66666667f;
  float w2 = fmaf(0.5f, s3, -s2) + 0.66666667f;
  uint32_t u01 = __builtin_bit_cast(uint32_t, __builtin_amdgcn_cvt_pkrtz(w0, w1));
  uint32_t u23 = __builtin_bit_cast(uint32_t, __builtin_amdgcn_cvt_pkrtz(w2, w3));
  uint64_t V = (uint64_t)u01 | ((uint64_t)u23 << 32);
  uint32_t vl = (uint32_t)(V << 16);
  u32x4 fr;
#pragma unroll
  for (int q = 0; q < 4; ++q) {
    int d = i - 2 * q;
    uint32_t rr = (uint32_t)(V >> ((48 - 16 * d) & 63));
    fr[q] = ((uint32_t)d <= 3u) ? rr : ((d == 4) ? vl : 0u);
  }
  return __builtin_bit_cast(half8, fr);
}

// ------------- fused prep: basis table (blocks 0..8191) + weights -------------
// weight layout for 16x16x32 MFMA B-frags (R4 layout):
// spline K-order kt = ii*24 + jj*8 + g; quad q -> channel c = 4g+q; f = 9c+3ii+jj
// base kt>=72: natural feature order.
__global__ void prep_all(const float* __restrict__ x,
                         const float* __restrict__ bw,
                         const float* __restrict__ sw,
                         const float* __restrict__ sc,
                         half8* __restrict__ bsp,
                         half8* __restrict__ bfrag) {
  int bid = blockIdx.x;
  if (bid < 8192) {                            // basis: one elem per thread
    int i = bid * 256 + threadIdx.x;
    bsp[i] = bspline8(x[i]);
    return;
  }
  int t = (bid - 8192) * 256 + threadIdx.x;    // 0..20735
  half8 v;
  int dst;
  if (t < NOUT * FIN) {                        // spline (o,f) pairs
    int o = t / FIN;
    int f = t - o * FIN;
    float scale = sc[t];
    const float* p = sw + t * 8;
#pragma unroll
    for (int c = 0; c < 8; ++c) v[c] = (_Float16)(p[c] * scale);
    int ch = f / 9;
    int r  = f - ch * 9;
    int ii = r / 3;
    int jj = r - ii * 3;
    int g  = ch >> 2, q = ch & 3;
    int kt = ii * 24 + jj * 8 + g;
    dst = (kt * 4 + (o >> 4)) * 64 + q * 16 + (o & 15);
  } else {                                     // base frag-lanes
    int t2 = t - NOUT * FIN;
    int lane = t2 & 63;
    int nf = (t2 >> 6) & 3;
    int ktb = t2 >> 8;                         // 0..8
    int o = nf * 16 + (lane & 15);
    int f0 = ktb * 32 + (lane >> 4) * 8;
    const float* p = bw + o * FIN + f0;
#pragma unroll
    for (int c = 0; c < 8; ++c) v[c] = (_Float16)p[c];
    dst = ((KSPL + ktb) * 4 + nf) * 64 + lane;
  }
  bfrag[dst] = v;
}

// ---------------- main: pure load + MFMA, XCD-swizzled ----------------
// 961 blocks x 4 waves; wave = 16 px x 64 outs. Swizzle: contiguous 120-block
// (~2-image, ~4.2 MB bsp) ranges per XCD so unfold re-reads hit per-XCD L2.
__global__ __launch_bounds__(256, 4) void kan_main2(
    const float* __restrict__ x,
    const half8* __restrict__ bsp,
    const half8* __restrict__ bfrag,
    float* __restrict__ out) {
  const int lane = threadIdx.x & 63;
  const int wv   = threadIdx.x >> 6;
  const int quad = lane >> 4;
  const int m16  = lane & 15;

  const int bid  = blockIdx.x;
  const int tile = (bid < 960) ? ((bid & 7) * 120 + (bid >> 3)) : 960;

  const int px = tile * 64 + wv * 16 + m16;  // < 61504 exactly
  const int b  = px / LPB;
  const int l  = px - b * LPB;
  const int ho = l / 62;
  const int wo = l - ho * 62;
  const int xbase = b * 131072 + ho * 64 + wo;     // elem idx ([b][c][h][w])

  f32x4 acc[4];
#pragma unroll
  for (int nf = 0; nf < 4; ++nf) acc[nf] = (f32x4){0.f, 0.f, 0.f, 0.f};

  const half8* abase = bsp + xbase + quad * 4096;  // channel = 4g + quad

  // ---- spline K: kt = ii*24 + jj*8 + g ----
  int kt = 0;
#pragma unroll
  for (int ii = 0; ii < 3; ++ii) {
#pragma unroll
    for (int jj = 0; jj < 3; ++jj) {
      const half8* ap = abase + ii * 64 + jj;
#pragma unroll
      for (int g = 0; g < 8; ++g) {
        half8 af = ap[g * 16384];                  // +4 channels per g
#pragma unroll
        for (int nf = 0; nf < 4; ++nf) {
          half8 bf = bfrag[(kt * 4 + nf) * 64 + lane];
          acc[nf] = __builtin_amdgcn_mfma_f32_16x16x32_f16(af, bf, acc[nf], 0, 0, 0);
        }
        ++kt;
      }
    }
  }

  // ---- base K: relu(x), natural feature order ----
#pragma unroll
  for (int kb = 0; kb < 9; ++kb) {
    int f0 = kb * 32 + quad * 8;
    half8 a;
#pragma unroll
    for (int j = 0; j < 8; ++j) {
      int f = f0 + j;
      int c = (f * 57) >> 9;            // f/9 (f<512)
      int r = f - c * 9;
      int i2 = (r * 11) >> 5;           // r/3 (r<9)
      int j2 = r - i2 * 3;
      a[j] = (_Float16)fmaxf(x[xbase + c * 4096 + i2 * 64 + j2], 0.0f);
    }
#pragma unroll
    for (int nf = 0; nf < 4; ++nf) {
      half8 bf = bfrag[((KSPL + kb) * 4 + nf) * 64 + lane];
      acc[nf] = __builtin_amdgcn_mfma_f32_16x16x32_f16(a, bf, acc[nf], 0, 0, 0);
    }
  }

  // ---- epilogue: col(out)=m16, row(pixel)=quad*4+rg ----
#pragma unroll
  for (int rg = 0; rg < 4; ++rg) {
    int p2 = tile * 64 + wv * 16 + quad * 4 + rg;
    int b2 = p2 / LPB;
    int l2 = p2 - b2 * LPB;
    float* ob = out + b2 * (NOUT * LPB) + l2;
#pragma unroll
    for (int nf = 0; nf < 4; ++nf) {
      int o = nf * 16 + m16;
      ob[o * LPB] = acc[nf][rg];
    }
  }
}

extern "C" void kernel_launch(void* const* d_in, const int* in_sizes, int n_in,
                              void* d_out, int out_size, void* d_ws, size_t ws_size,
                              hipStream_t stream) {
  const float* x  = (const float*)d_in[0];
  const float* bw = (const float*)d_in[1];  // (64, 288)
  const float* sw = (const float*)d_in[2];  // (64, 288, 8)
  const float* sc = (const float*)d_in[3];  // (64, 288)
  float* out = (float*)d_out;
  half8* bfrag = (half8*)d_ws;                           // 331,776 B (padded)
  half8* bsp   = (half8*)((char*)d_ws + BFRAG_BYTES);    // 33.5 MB basis table

  prep_all<<<8192 + 81, 256, 0, stream>>>(x, bw, sw, sc, bsp, bfrag);
  kan_main2<<<NPIX / 64, 256, 0, stream>>>(x, bsp, bfrag, out);
}